// Round 3
// baseline (4578.371 us; speedup 1.0000x reference)
//
#include <hip/hip_runtime.h>
#include <stdint.h>

// ---------------------------------------------------------------------------
// MD5Surrogate: 64-round scan of a 3-layer MLP (22->256->256->16), B=16384.
// Dtype-ADAPTIVE: detects at runtime whether inputs are fp32 or bf16 (wave-
// uniform ballot over W2's even ushorts — fp32 low-mantissa-halves decode as
// huge bf16s, real bf16 weights never do). Weights rounded to bf16 for MFMA;
// activations/biases/msg/state carried in fp32 precision via bf16 (hi,lo)
// split pairs in LDS. fp32 accumulate, exact-erf gelu. d_ws untouched.
// ---------------------------------------------------------------------------

using bf16x8  = __attribute__((ext_vector_type(8))) __bf16;
using floatx4 = __attribute__((ext_vector_type(4))) float;
using ushort4v = __attribute__((ext_vector_type(4))) unsigned short;

__constant__ int c_sched[64] = {
  0,1,2,3,4,5,6,7,8,9,10,11,12,13,14,15,
  1,6,11,0,5,10,15,4,9,14,3,8,13,2,7,12,
  5,8,11,14,1,4,7,10,13,0,3,6,9,12,15,2,
  0,7,14,5,12,3,10,1,8,15,6,13,4,11,2,9
};
__constant__ float c_shift[64] = {
  7,12,17,22,7,12,17,22,7,12,17,22,7,12,17,22,
  5,9,14,20,5,9,14,20,5,9,14,20,5,9,14,20,
  4,11,16,23,4,11,16,23,4,11,16,23,4,11,16,23,
  6,10,15,21,6,10,15,21,6,10,15,21,6,10,15,21
};

__device__ __forceinline__ unsigned short f2bf(float x) {
  union { float f; unsigned u; } v; v.f = x;
  unsigned r = v.u + 0x7fffu + ((v.u >> 16) & 1u);
  return (unsigned short)(r >> 16);
}
__device__ __forceinline__ float bf2f(unsigned short h) {
  union { unsigned u; float f; } v; v.u = ((unsigned)h) << 16;
  return v.f;
}
// dtype-adaptive scalar loads
__device__ __forceinline__ float ldf(const void* p, int idx, bool f32) {
  return f32 ? ((const float*)p)[idx] : bf2f(((const unsigned short*)p)[idx]);
}
__device__ __forceinline__ unsigned short ldb(const void* p, int idx, bool f32) {
  return f32 ? f2bf(((const float*)p)[idx]) : ((const unsigned short*)p)[idx];
}
// exact gelu: 0.5*x*(1+erf(x/sqrt(2))), erf via Abramowitz-Stegun 7.1.26
__device__ __forceinline__ float gelu_f(float x) {
  float ax = fabsf(x) * 0.7071067811865476f;
  float t  = __builtin_amdgcn_rcpf(1.0f + 0.3275911f * ax);
  float poly = t*(0.254829592f + t*(-0.284496736f + t*(1.421413741f +
               t*(-1.453152027f + t*1.061405429f))));
  float e  = __expf(-ax*ax);
  float er = 1.0f - poly*e;
  er = copysignf(er, x);
  return 0.5f * x * (1.0f + er);
}

__device__ __forceinline__ floatx4 mfma16(bf16x8 a, bf16x8 b, floatx4 c) {
  return __builtin_amdgcn_mfma_f32_16x16x32_bf16(a, b, c, 0, 0, 0);
}

#define STRIDE_H 264   // ushorts; 528B rows -> 16B aligned

__device__ __forceinline__ void epi_store(floatx4 acc, const float* bb,
                                          unsigned short* hp, unsigned short* lp) {
  ushort4v hi4, lo4;
  #pragma unroll
  for (int e = 0; e < 4; ++e) {
    float vv = acc[e] + bb[e];
    float g  = gelu_f(vv);
    unsigned short h = f2bf(g);
    hi4[e] = h;
    lo4[e] = f2bf(g - bf2f(h));
  }
  *(ushort4v*)hp = hi4;
  *(ushort4v*)lp = lo4;
}

__global__ __launch_bounds__(256, 2) void md5_kernel(
    const void* __restrict__ msg,   // (16384,64)
    const void* __restrict__ st0,   // (16384,16)
    const void* __restrict__ W1,    // (64,22,256)
    const void* __restrict__ b1,    // (64,256)
    const void* __restrict__ W2,    // (64,256,256)
    const void* __restrict__ b2,    // (64,256)
    const void* __restrict__ W3,    // (64,256,16)
    const void* __restrict__ b3,    // (64,16)
    void* __restrict__ out)         // (16384,16)
{
  __shared__ unsigned short xhi[32][32], xlo[32][32];
  __shared__ unsigned short hhi[32][STRIDE_H], hlo[32][STRIDE_H];
  __shared__ float pbuf[2][4][16][16];
  __shared__ unsigned short msgb[32][64], msgl[32][64];

  const int tid  = threadIdx.x;
  const int wv   = tid >> 6;
  const int lane = tid & 63;
  const int q    = lane >> 4;
  const int ln   = lane & 15;
  const int row0 = blockIdx.x * 32;

  // ---- dtype detection: even ushorts of fp32 data decode as wild bf16s ----
  bool isf32;
  {
    unsigned short u = ((const unsigned short*)W2)[4096 + 2*lane];
    bool crazy = ((u >> 7) & 0xFF) >= 0x88;    // |bf16| >= 2^9
    isf32 = __popcll(__ballot(crazy)) >= 4;
  }

  // ---- zero ALL LDS once ----
  for (int i = tid; i < 32*32; i += 256) { (&xhi[0][0])[i] = 0; (&xlo[0][0])[i] = 0; }
  for (int i = tid; i < 32*STRIDE_H; i += 256) { (&hhi[0][0])[i] = 0; (&hlo[0][0])[i] = 0; }
  for (int i = tid; i < 2*4*16*16; i += 256) (&pbuf[0][0][0][0])[i] = 0.0f;
  __syncthreads();

  // ---- preload message tile (hi/lo split) ----
  {
    int base = tid * 8;                // 2048 elements / 256 thr
    int rr = base >> 6, cc = base & 63;
    #pragma unroll
    for (int j = 0; j < 8; ++j) {
      float v = ldf(msg, (row0 + rr)*64 + cc + j, isf32);
      unsigned short h = f2bf(v);
      msgb[rr][cc + j] = h;
      msgl[rr][cc + j] = f2bf(v - bf2f(h));
    }
  }
  __syncthreads();

  // ---- init x buffer: 0..15 state, 16..19 word, 20..21 rinfo, 22..31 zero --
  if (wv < 2) {
    int n = wv*16 + ln;
    #pragma unroll
    for (int e = 0; e < 4; ++e) {
      float v = ldf(st0, (row0 + n)*16 + 4*q + e, isf32);
      unsigned short h = f2bf(v);
      xhi[n][4*q + e] = h;
      xlo[n][4*q + e] = f2bf(v - bf2f(h));
    }
  } else if (wv == 2) {
    if (lane < 32) {
      int n = lane;
      int s = c_sched[0];
      float i1 = c_shift[0] / 25.0f;
      unsigned short i1h = f2bf(i1);
      unsigned short i1l = f2bf(i1 - bf2f(i1h));
      #pragma unroll
      for (int j = 0; j < 4; ++j) {
        xhi[n][16 + j] = msgb[n][4*s + j];
        xlo[n][16 + j] = msgl[n][4*s + j];
      }
      xhi[n][20] = 0;  xlo[n][20] = 0;   // round 0: i/64 = 0
      xhi[n][21] = i1h; xlo[n][21] = i1l;
      // 22..31 stay zero
    }
  }

  #pragma unroll 1
  for (int r = 0; r < 64; ++r) {
    __syncthreads();   // xbuf ready

    // ----------------- Layer 1: x(22) @ W1 -> h1(256) -----------------
    bf16x8 bxh[2], bxl[2];
    #pragma unroll
    for (int nt = 0; nt < 2; ++nt) {
      bxh[nt] = *(const bf16x8*)&xhi[nt*16 + ln][8*q];
      bxl[nt] = *(const bf16x8*)&xlo[nt*16 + ln][8*q];
    }
    #pragma unroll
    for (int tt = 0; tt < 4; ++tt) {
      int t = 4*wv + tt;
      union { unsigned short u[8]; bf16x8 v; } fa;
      #pragma unroll
      for (int j = 0; j < 8; ++j) {
        int k = 8*q + j;
        fa.u[j] = (k < 22) ? ldb(W1, (r*22 + k)*256 + 16*t + ln, isf32)
                           : (unsigned short)0;
      }
      floatx4 acc0 = {0,0,0,0}, acc1 = {0,0,0,0};
      acc0 = mfma16(fa.v, bxl[0], acc0);
      acc0 = mfma16(fa.v, bxh[0], acc0);
      acc1 = mfma16(fa.v, bxl[1], acc1);
      acc1 = mfma16(fa.v, bxh[1], acc1);
      int f0 = t*16 + 4*q;
      float bb[4];
      #pragma unroll
      for (int e = 0; e < 4; ++e) bb[e] = ldf(b1, r*256 + f0 + e, isf32);
      epi_store(acc0, bb, &hhi[ln][f0],      &hlo[ln][f0]);
      epi_store(acc1, bb, &hhi[16 + ln][f0], &hlo[16 + ln][f0]);
    }
    __syncthreads();   // h1 complete

    // ----------------- Layer 2: h1 @ W2 -> h2(256) -----------------
    bf16x8 Bh[2][8], Bl[2][8];
    #pragma unroll
    for (int nt = 0; nt < 2; ++nt)
      #pragma unroll
      for (int c = 0; c < 8; ++c) {
        Bh[nt][c] = *(const bf16x8*)&hhi[nt*16 + ln][32*c + 8*q];
        Bl[nt][c] = *(const bf16x8*)&hlo[nt*16 + ln][32*c + 8*q];
      }
    __syncthreads();   // all B-frag reads done -> hbuf writable

    #pragma unroll
    for (int tt = 0; tt < 4; ++tt) {
      int t = 4*wv + tt;
      floatx4 acc0 = {0,0,0,0}, acc1 = {0,0,0,0};
      #pragma unroll
      for (int c = 0; c < 8; ++c) {
        union { unsigned short u[8]; bf16x8 v; } fa;
        #pragma unroll
        for (int j = 0; j < 8; ++j)
          fa.u[j] = ldb(W2, (r*256 + 32*c + 8*q + j)*256 + 16*t + ln, isf32);
        acc0 = mfma16(fa.v, Bl[0][c], acc0);
        acc0 = mfma16(fa.v, Bh[0][c], acc0);
        acc1 = mfma16(fa.v, Bl[1][c], acc1);
        acc1 = mfma16(fa.v, Bh[1][c], acc1);
      }
      int f0 = t*16 + 4*q;
      float bb[4];
      #pragma unroll
      for (int e = 0; e < 4; ++e) bb[e] = ldf(b2, r*256 + f0 + e, isf32);
      epi_store(acc0, bb, &hhi[ln][f0],      &hlo[ln][f0]);
      epi_store(acc1, bb, &hhi[16 + ln][f0], &hlo[16 + ln][f0]);
    }
    __syncthreads();   // h2 complete

    // ------- Layer 3: h2 @ W3 -> state(16), partial-K per wave -------
    {
      floatx4 acc[2] = {{0,0,0,0},{0,0,0,0}};
      #pragma unroll
      for (int cc = 0; cc < 2; ++cc) {
        int c = 2*wv + cc;
        union { unsigned short u[8]; bf16x8 v; } fa;
        #pragma unroll
        for (int j = 0; j < 8; ++j)
          fa.u[j] = ldb(W3, (r*256 + 32*c + 8*q + j)*16 + ln, isf32);
        #pragma unroll
        for (int nt = 0; nt < 2; ++nt) {
          bf16x8 bh = *(const bf16x8*)&hhi[nt*16 + ln][32*c + 8*q];
          bf16x8 bl = *(const bf16x8*)&hlo[nt*16 + ln][32*c + 8*q];
          acc[nt] = mfma16(fa.v, bl, acc[nt]);
          acc[nt] = mfma16(fa.v, bh, acc[nt]);
        }
      }
      *(floatx4*)&pbuf[0][wv][ln][4*q] = acc[0];
      *(floatx4*)&pbuf[1][wv][ln][4*q] = acc[1];
    }
    __syncthreads();   // partials ready

    if (wv < 2) {
      int nt = wv;
      floatx4 s0 = *(const floatx4*)&pbuf[nt][0][ln][4*q];
      floatx4 s1 = *(const floatx4*)&pbuf[nt][1][ln][4*q];
      floatx4 s2 = *(const floatx4*)&pbuf[nt][2][ln][4*q];
      floatx4 s3 = *(const floatx4*)&pbuf[nt][3][ln][4*q];
      floatx4 s = s0 + s1 + s2 + s3;
      #pragma unroll
      for (int e = 0; e < 4; ++e) s[e] += ldf(b3, r*16 + 4*q + e, isf32);
      if (r == 63) {
        int oidx = (row0 + nt*16 + ln)*16 + 4*q;
        if (isf32) {
          *(floatx4*)((float*)out + oidx) = s;
        } else {
          ushort4v o = { f2bf(s[0]), f2bf(s[1]), f2bf(s[2]), f2bf(s[3]) };
          *(ushort4v*)((unsigned short*)out + oidx) = o;
        }
      } else {
        int n = nt*16 + ln;
        ushort4v hi4, lo4;
        #pragma unroll
        for (int e = 0; e < 4; ++e) {
          unsigned short h = f2bf(s[e]);
          hi4[e] = h;
          lo4[e] = f2bf(s[e] - bf2f(h));
        }
        *(ushort4v*)&xhi[n][4*q] = hi4;
        *(ushort4v*)&xlo[n][4*q] = lo4;
      }
    } else if (wv == 2) {
      if (lane < 32 && r < 63) {
        int n = lane;
        int s = c_sched[r+1];
        float i0 = (float)(r+1) * 0.015625f;       // exact in bf16
        float i1 = c_shift[r+1] / 25.0f;
        unsigned short i1h = f2bf(i1);
        unsigned short i1l = f2bf(i1 - bf2f(i1h));
        #pragma unroll
        for (int j = 0; j < 4; ++j) {
          xhi[n][16 + j] = msgb[n][4*s + j];
          xlo[n][16 + j] = msgl[n][4*s + j];
        }
        xhi[n][20] = f2bf(i0); xlo[n][20] = 0;
        xhi[n][21] = i1h;      xlo[n][21] = i1l;
      }
    }
  }
}

// ---------------------------------------------------------------------------
extern "C" void kernel_launch(void* const* d_in, const int* in_sizes, int n_in,
                              void* d_out, int out_size, void* d_ws, size_t ws_size,
                              hipStream_t stream) {
  (void)d_ws; (void)ws_size; (void)in_sizes; (void)n_in; (void)out_size;
  md5_kernel<<<512, 256, 0, stream>>>(d_in[0], d_in[1], d_in[2], d_in[3],
                                      d_in[4], d_in[5], d_in[6], d_in[7], d_out);
}

// Round 4
// 897.464 us; speedup vs baseline: 5.1015x; 5.1015x over previous
//
#include <hip/hip_runtime.h>
#include <stdint.h>

// ---------------------------------------------------------------------------
// MD5Surrogate: 64-round scan of a 3-layer MLP (22->256->256->16), B=16384.
// Inputs/outputs are fp32 (confirmed R3). This revision:
//  * pack_w prep kernel: fp32 weights -> bf16 MFMA A-fragment order in d_ws
//    (9.96 MB); main-loop A-frags become single global_load_dwordx4.
//  * host falls back to direct-gather variant if ws_size too small.
//  * activations in LDS as bf16 (hi,lo) split pairs (fp32-exact products),
//    fp32 accumulate, exact-erf gelu, fp32 vector bias loads & output.
// ---------------------------------------------------------------------------

using bf16x8   = __attribute__((ext_vector_type(8))) __bf16;
using floatx4  = __attribute__((ext_vector_type(4))) float;
using ushort4v = __attribute__((ext_vector_type(4))) unsigned short;

__constant__ int c_sched[64] = {
  0,1,2,3,4,5,6,7,8,9,10,11,12,13,14,15,
  1,6,11,0,5,10,15,4,9,14,3,8,13,2,7,12,
  5,8,11,14,1,4,7,10,13,0,3,6,9,12,15,2,
  0,7,14,5,12,3,10,1,8,15,6,13,4,11,2,9
};
__constant__ float c_shift[64] = {
  7,12,17,22,7,12,17,22,7,12,17,22,7,12,17,22,
  5,9,14,20,5,9,14,20,5,9,14,20,5,9,14,20,
  4,11,16,23,4,11,16,23,4,11,16,23,4,11,16,23,
  6,10,15,21,6,10,15,21,6,10,15,21,6,10,15,21
};

__device__ __forceinline__ unsigned short f2bf(float x) {
  union { float f; unsigned u; } v; v.f = x;
  unsigned r = v.u + 0x7fffu + ((v.u >> 16) & 1u);
  return (unsigned short)(r >> 16);
}
__device__ __forceinline__ float bf2f(unsigned short h) {
  union { unsigned u; float f; } v; v.u = ((unsigned)h) << 16;
  return v.f;
}
// exact gelu: 0.5*x*(1+erf(x/sqrt(2))), erf via Abramowitz-Stegun 7.1.26
__device__ __forceinline__ float gelu_f(float x) {
  float ax = fabsf(x) * 0.7071067811865476f;
  float t  = __builtin_amdgcn_rcpf(1.0f + 0.3275911f * ax);
  float poly = t*(0.254829592f + t*(-0.284496736f + t*(1.421413741f +
               t*(-1.453152027f + t*1.061405429f))));
  float e  = __expf(-ax*ax);
  float er = 1.0f - poly*e;
  er = copysignf(er, x);
  return 0.5f * x * (1.0f + er);
}

__device__ __forceinline__ floatx4 mfma16(bf16x8 a, bf16x8 b, floatx4 c) {
  return __builtin_amdgcn_mfma_f32_16x16x32_bf16(a, b, c, 0, 0, 0);
}

// ---------------------------------------------------------------------------
// Packed-weight layout (ushorts): fragment = 64 lanes x 8 bf16 (1 KB).
// A[m][k]: m = lane&15, k = 8*(lane>>4)+j.
//   P1 frag (r*16+t):        W1[r][k][16t+m], k>=22 -> 0.   1024 frags
//   P2 frag ((r*16+t)*8+c):  W2[r][32c+k'][16t+m]           8192 frags
//   P3 frag (r*8+c):         W3[r][32c+k'][m]                512 frags
// ---------------------------------------------------------------------------
#define N1G (64*16*64)        // frag-lane groups
#define N2G (64*16*8*64)
#define N3G (64*8*64)
#define PACK_USHORTS ((size_t)(N1G + N2G + N3G) * 8)
#define PACK_BYTES   (PACK_USHORTS * 2)

__global__ void pack_w(const float* __restrict__ W1,
                       const float* __restrict__ W2,
                       const float* __restrict__ W3,
                       unsigned short* __restrict__ P) {
  int gid = blockIdx.x * blockDim.x + threadIdx.x;
  if (gid >= N1G + N2G + N3G) return;
  unsigned short v[8];
  unsigned short* dst;
  if (gid < N1G) {
    int lane = gid & 63, t = (gid >> 6) & 15, r = gid >> 10;
    int q = lane >> 4, mm = lane & 15;
    #pragma unroll
    for (int j = 0; j < 8; ++j) {
      int k = 8*q + j;
      v[j] = (k < 22) ? f2bf(W1[(r*22 + k)*256 + 16*t + mm]) : (unsigned short)0;
    }
    dst = P + (size_t)gid * 8;
  } else if (gid < N1G + N2G) {
    int g = gid - N1G;
    int lane = g & 63, c = (g >> 6) & 7, t = (g >> 9) & 15, r = g >> 13;
    int q = lane >> 4, mm = lane & 15;
    #pragma unroll
    for (int j = 0; j < 8; ++j) {
      int k = 32*c + 8*q + j;
      v[j] = f2bf(W2[((size_t)r*256 + k)*256 + 16*t + mm]);
    }
    dst = P + (size_t)(N1G + g) * 8;
  } else {
    int g = gid - N1G - N2G;
    int lane = g & 63, c = (g >> 6) & 7, r = g >> 9;
    int q = lane >> 4, mm = lane & 15;
    #pragma unroll
    for (int j = 0; j < 8; ++j) {
      int k = 32*c + 8*q + j;
      v[j] = f2bf(W3[(r*256 + k)*16 + mm]);
    }
    dst = P + (size_t)(N1G + N2G + g) * 8;
  }
  ushort4v lo = { v[0],v[1],v[2],v[3] }, hi = { v[4],v[5],v[6],v[7] };
  *(ushort4v*)dst = lo;
  *(ushort4v*)(dst + 4) = hi;
}

// ---------------------------------------------------------------------------
#define STRIDE_H 264   // ushorts; 528B rows -> 16B aligned

__device__ __forceinline__ void epi_store(floatx4 acc, floatx4 bb,
                                          unsigned short* hp, unsigned short* lp) {
  ushort4v hi4, lo4;
  #pragma unroll
  for (int e = 0; e < 4; ++e) {
    float g  = gelu_f(acc[e] + bb[e]);
    unsigned short h = f2bf(g);
    hi4[e] = h;
    lo4[e] = f2bf(g - bf2f(h));
  }
  *(ushort4v*)hp = hi4;
  *(ushort4v*)lp = lo4;
}

template<bool PACKED>
__global__ __launch_bounds__(256, 2) void md5_main(
    const float* __restrict__ msg,   // (16384,64)
    const float* __restrict__ st0,   // (16384,16)
    const float* __restrict__ W1,    // (64,22,256)
    const float* __restrict__ b1,    // (64,256)
    const float* __restrict__ W2,    // (64,256,256)
    const float* __restrict__ b2,    // (64,256)
    const float* __restrict__ W3,    // (64,256,16)
    const float* __restrict__ b3,    // (64,16)
    const unsigned short* __restrict__ P,   // packed weights (PACKED only)
    float* __restrict__ out)         // (16384,16)
{
  __shared__ unsigned short xhi[32][32], xlo[32][32];
  __shared__ unsigned short hhi[32][STRIDE_H], hlo[32][STRIDE_H];
  __shared__ float pbuf[2][4][16][16];
  __shared__ unsigned short msgb[32][64], msgl[32][64];

  const int tid  = threadIdx.x;
  const int wv   = tid >> 6;
  const int lane = tid & 63;
  const int q    = lane >> 4;
  const int ln   = lane & 15;
  const int row0 = blockIdx.x * 32;

  const unsigned short* P1 = P;
  const unsigned short* P2 = P + (size_t)N1G * 8;
  const unsigned short* P3 = P + (size_t)(N1G + N2G) * 8;

  // ---- zero LDS x-pad region + pbuf once ----
  for (int i = tid; i < 32*32; i += 256) { (&xhi[0][0])[i] = 0; (&xlo[0][0])[i] = 0; }
  __syncthreads();

  // ---- preload message tile (hi/lo split), fp32 vector loads ----
  {
    int base = tid * 8;                // 2048 elements / 256 thr
    int rr = base >> 6, cc = base & 63;
    floatx4 v0 = *(const floatx4*)(msg + (size_t)(row0 + rr)*64 + cc);
    floatx4 v1 = *(const floatx4*)(msg + (size_t)(row0 + rr)*64 + cc + 4);
    #pragma unroll
    for (int j = 0; j < 4; ++j) {
      unsigned short h0 = f2bf(v0[j]), h1 = f2bf(v1[j]);
      msgb[rr][cc + j]     = h0;  msgl[rr][cc + j]     = f2bf(v0[j] - bf2f(h0));
      msgb[rr][cc + 4 + j] = h1;  msgl[rr][cc + 4 + j] = f2bf(v1[j] - bf2f(h1));
    }
  }
  __syncthreads();

  // ---- init x: 0..15 state, 16..19 word, 20..21 rinfo, 22..31 zero ----
  if (wv < 2) {
    int n = wv*16 + ln;
    floatx4 v = *(const floatx4*)(st0 + (size_t)(row0 + n)*16 + 4*q);
    #pragma unroll
    for (int e = 0; e < 4; ++e) {
      unsigned short h = f2bf(v[e]);
      xhi[n][4*q + e] = h;
      xlo[n][4*q + e] = f2bf(v[e] - bf2f(h));
    }
  } else if (wv == 2) {
    if (lane < 32) {
      int n = lane;
      int s = c_sched[0];
      float i1 = c_shift[0] / 25.0f;
      unsigned short i1h = f2bf(i1);
      unsigned short i1l = f2bf(i1 - bf2f(i1h));
      #pragma unroll
      for (int j = 0; j < 4; ++j) {
        xhi[n][16 + j] = msgb[n][4*s + j];
        xlo[n][16 + j] = msgl[n][4*s + j];
      }
      xhi[n][20] = 0;   xlo[n][20] = 0;   // round 0: i/64 = 0
      xhi[n][21] = i1h; xlo[n][21] = i1l;
    }
  }

  #pragma unroll 1
  for (int r = 0; r < 64; ++r) {
    __syncthreads();   // xbuf ready

    // ----------------- Layer 1: x(22) @ W1 -> h1(256) -----------------
    bf16x8 bxh[2], bxl[2];
    #pragma unroll
    for (int nt = 0; nt < 2; ++nt) {
      bxh[nt] = *(const bf16x8*)&xhi[nt*16 + ln][8*q];
      bxl[nt] = *(const bf16x8*)&xlo[nt*16 + ln][8*q];
    }
    #pragma unroll
    for (int tt = 0; tt < 4; ++tt) {
      int t = 4*wv + tt;
      bf16x8 fa;
      if (PACKED) {
        fa = *(const bf16x8*)(P1 + ((size_t)(r*16 + t)*64 + lane)*8);
      } else {
        union { unsigned short u[8]; bf16x8 v; } fu;
        #pragma unroll
        for (int j = 0; j < 8; ++j) {
          int k = 8*q + j;
          fu.u[j] = (k < 22) ? f2bf(W1[(r*22 + k)*256 + 16*t + ln]) : (unsigned short)0;
        }
        fa = fu.v;
      }
      floatx4 acc0 = {0,0,0,0}, acc1 = {0,0,0,0};
      acc0 = mfma16(fa, bxl[0], acc0);
      acc0 = mfma16(fa, bxh[0], acc0);
      acc1 = mfma16(fa, bxl[1], acc1);
      acc1 = mfma16(fa, bxh[1], acc1);
      int f0 = t*16 + 4*q;
      floatx4 bb = *(const floatx4*)(b1 + r*256 + f0);
      epi_store(acc0, bb, &hhi[ln][f0],      &hlo[ln][f0]);
      epi_store(acc1, bb, &hhi[16 + ln][f0], &hlo[16 + ln][f0]);
    }
    __syncthreads();   // h1 complete

    // ----------------- Layer 2: h1 @ W2 -> h2(256) -----------------
    bf16x8 Bh[2][8], Bl[2][8];
    #pragma unroll
    for (int nt = 0; nt < 2; ++nt)
      #pragma unroll
      for (int c = 0; c < 8; ++c) {
        Bh[nt][c] = *(const bf16x8*)&hhi[nt*16 + ln][32*c + 8*q];
        Bl[nt][c] = *(const bf16x8*)&hlo[nt*16 + ln][32*c + 8*q];
      }
    __syncthreads();   // all B-frag reads done -> hbuf writable

    #pragma unroll
    for (int tt = 0; tt < 4; ++tt) {
      int t = 4*wv + tt;
      floatx4 acc0 = {0,0,0,0}, acc1 = {0,0,0,0};
      #pragma unroll
      for (int c = 0; c < 8; ++c) {
        bf16x8 fa;
        if (PACKED) {
          fa = *(const bf16x8*)(P2 + ((size_t)((r*16 + t)*8 + c)*64 + lane)*8);
        } else {
          union { unsigned short u[8]; bf16x8 v; } fu;
          #pragma unroll
          for (int j = 0; j < 8; ++j)
            fu.u[j] = f2bf(W2[((size_t)(r*256 + 32*c + 8*q + j))*256 + 16*t + ln]);
          fa = fu.v;
        }
        acc0 = mfma16(fa, Bl[0][c], acc0);
        acc0 = mfma16(fa, Bh[0][c], acc0);
        acc1 = mfma16(fa, Bl[1][c], acc1);
        acc1 = mfma16(fa, Bh[1][c], acc1);
      }
      int f0 = t*16 + 4*q;
      floatx4 bb = *(const floatx4*)(b2 + r*256 + f0);
      epi_store(acc0, bb, &hhi[ln][f0],      &hlo[ln][f0]);
      epi_store(acc1, bb, &hhi[16 + ln][f0], &hlo[16 + ln][f0]);
    }
    __syncthreads();   // h2 complete

    // ------- Layer 3: h2 @ W3 -> state(16), partial-K per wave -------
    {
      floatx4 acc[2] = {{0,0,0,0},{0,0,0,0}};
      #pragma unroll
      for (int cc = 0; cc < 2; ++cc) {
        int c = 2*wv + cc;
        bf16x8 fa;
        if (PACKED) {
          fa = *(const bf16x8*)(P3 + ((size_t)(r*8 + c)*64 + lane)*8);
        } else {
          union { unsigned short u[8]; bf16x8 v; } fu;
          #pragma unroll
          for (int j = 0; j < 8; ++j)
            fu.u[j] = f2bf(W3[(r*256 + 32*c + 8*q + j)*16 + ln]);
          fa = fu.v;
        }
        #pragma unroll
        for (int nt = 0; nt < 2; ++nt) {
          bf16x8 bh = *(const bf16x8*)&hhi[nt*16 + ln][32*c + 8*q];
          bf16x8 bl = *(const bf16x8*)&hlo[nt*16 + ln][32*c + 8*q];
          acc[nt] = mfma16(fa, bl, acc[nt]);
          acc[nt] = mfma16(fa, bh, acc[nt]);
        }
      }
      *(floatx4*)&pbuf[0][wv][ln][4*q] = acc[0];
      *(floatx4*)&pbuf[1][wv][ln][4*q] = acc[1];
    }
    __syncthreads();   // partials ready

    if (wv < 2) {
      int nt = wv;
      floatx4 s0 = *(const floatx4*)&pbuf[nt][0][ln][4*q];
      floatx4 s1 = *(const floatx4*)&pbuf[nt][1][ln][4*q];
      floatx4 s2 = *(const floatx4*)&pbuf[nt][2][ln][4*q];
      floatx4 s3 = *(const floatx4*)&pbuf[nt][3][ln][4*q];
      floatx4 s = (s0 + s1) + (s2 + s3);
      floatx4 bb = *(const floatx4*)(b3 + r*16 + 4*q);
      s += bb;
      if (r == 63) {
        *(floatx4*)(out + (size_t)(row0 + nt*16 + ln)*16 + 4*q) = s;
      } else {
        int n = nt*16 + ln;
        ushort4v hi4, lo4;
        #pragma unroll
        for (int e = 0; e < 4; ++e) {
          unsigned short h = f2bf(s[e]);
          hi4[e] = h;
          lo4[e] = f2bf(s[e] - bf2f(h));
        }
        *(ushort4v*)&xhi[n][4*q] = hi4;
        *(ushort4v*)&xlo[n][4*q] = lo4;
      }
    } else if (wv == 2) {
      if (lane < 32 && r < 63) {
        int n = lane;
        int s = c_sched[r+1];
        float i0 = (float)(r+1) * 0.015625f;       // exact in bf16
        float i1 = c_shift[r+1] / 25.0f;
        unsigned short i1h = f2bf(i1);
        unsigned short i1l = f2bf(i1 - bf2f(i1h));
        #pragma unroll
        for (int j = 0; j < 4; ++j) {
          xhi[n][16 + j] = msgb[n][4*s + j];
          xlo[n][16 + j] = msgl[n][4*s + j];
        }
        xhi[n][20] = f2bf(i0); xlo[n][20] = 0;
        xhi[n][21] = i1h;      xlo[n][21] = i1l;
      }
    }
  }
}

// ---------------------------------------------------------------------------
extern "C" void kernel_launch(void* const* d_in, const int* in_sizes, int n_in,
                              void* d_out, int out_size, void* d_ws, size_t ws_size,
                              hipStream_t stream) {
  const float* msg = (const float*)d_in[0];
  const float* st0 = (const float*)d_in[1];
  const float* W1  = (const float*)d_in[2];
  const float* b1  = (const float*)d_in[3];
  const float* W2  = (const float*)d_in[4];
  const float* b2  = (const float*)d_in[5];
  const float* W3  = (const float*)d_in[6];
  const float* b3  = (const float*)d_in[7];
  float* out = (float*)d_out;
  (void)in_sizes; (void)n_in; (void)out_size;

  if (ws_size >= PACK_BYTES) {
    unsigned short* P = (unsigned short*)d_ws;
    const int totalGroups = N1G + N2G + N3G;   // 622592
    pack_w<<<(totalGroups + 255) / 256, 256, 0, stream>>>(W1, W2, W3, P);
    md5_main<true><<<512, 256, 0, stream>>>(msg, st0, W1, b1, W2, b2, W3, b3, P, out);
  } else {
    md5_main<false><<<512, 256, 0, stream>>>(msg, st0, W1, b1, W2, b2, W3, b3,
                                             nullptr, out);
  }
}

// Round 5
// 815.259 us; speedup vs baseline: 5.6158x; 1.1008x over previous
//
#include <hip/hip_runtime.h>
#include <stdint.h>

// ---------------------------------------------------------------------------
// MD5Surrogate: 64-round scan of a 3-layer MLP (22->256->256->16), B=16384.
// fp32 in/out. R5: bf16 activations for h1/h2 (hi-only), hi/lo split kept for
// the carried state x + message words (the compounding path). 16 rows/block,
// 1024 blocks, 4 blocks/CU. 3 barriers/round, double-buffered h, single-wave
// full-K layer 3 (no pbuf -> no 4-way bank conflicts). Weights packed to bf16
// MFMA A-fragment order in d_ws by pack_w.
// ---------------------------------------------------------------------------

using bf16x8   = __attribute__((ext_vector_type(8))) __bf16;
using floatx4  = __attribute__((ext_vector_type(4))) float;
using ushort4v = __attribute__((ext_vector_type(4))) unsigned short;

__constant__ int c_sched[64] = {
  0,1,2,3,4,5,6,7,8,9,10,11,12,13,14,15,
  1,6,11,0,5,10,15,4,9,14,3,8,13,2,7,12,
  5,8,11,14,1,4,7,10,13,0,3,6,9,12,15,2,
  0,7,14,5,12,3,10,1,8,15,6,13,4,11,2,9
};
__constant__ float c_shift[64] = {
  7,12,17,22,7,12,17,22,7,12,17,22,7,12,17,22,
  5,9,14,20,5,9,14,20,5,9,14,20,5,9,14,20,
  4,11,16,23,4,11,16,23,4,11,16,23,4,11,16,23,
  6,10,15,21,6,10,15,21,6,10,15,21,6,10,15,21
};

__device__ __forceinline__ unsigned short f2bf(float x) {
  union { float f; unsigned u; } v; v.f = x;
  unsigned r = v.u + 0x7fffu + ((v.u >> 16) & 1u);
  return (unsigned short)(r >> 16);
}
__device__ __forceinline__ float bf2f(unsigned short h) {
  union { unsigned u; float f; } v; v.u = ((unsigned)h) << 16;
  return v.f;
}
// exact gelu: 0.5*x*(1+erf(x/sqrt(2))), erf via Abramowitz-Stegun 7.1.26
__device__ __forceinline__ float gelu_f(float x) {
  float ax = fabsf(x) * 0.7071067811865476f;
  float t  = __builtin_amdgcn_rcpf(1.0f + 0.3275911f * ax);
  float poly = t*(0.254829592f + t*(-0.284496736f + t*(1.421413741f +
               t*(-1.453152027f + t*1.061405429f))));
  float e  = __expf(-ax*ax);
  float er = 1.0f - poly*e;
  er = copysignf(er, x);
  return 0.5f * x * (1.0f + er);
}

__device__ __forceinline__ floatx4 mfma16(bf16x8 a, bf16x8 b, floatx4 c) {
  return __builtin_amdgcn_mfma_f32_16x16x32_bf16(a, b, c, 0, 0, 0);
}

// ---------------------------------------------------------------------------
// Packed-weight layout (ushorts): fragment = 64 lanes x 8 bf16 (1 KB).
// A[m][k]: m = lane&15, k = 8*(lane>>4)+j.
//   P1 frag (r*16+t):        W1[r][k][16t+m], k>=22 -> 0
//   P2 frag ((r*16+t)*8+c):  W2[r][32c+k'][16t+m]
//   P3 frag (r*8+c):         W3[r][32c+k'][m]
// ---------------------------------------------------------------------------
#define N1G (64*16*64)
#define N2G (64*16*8*64)
#define N3G (64*8*64)
#define PACK_USHORTS ((size_t)(N1G + N2G + N3G) * 8)
#define PACK_BYTES   (PACK_USHORTS * 2)

__global__ void pack_w(const float* __restrict__ W1,
                       const float* __restrict__ W2,
                       const float* __restrict__ W3,
                       unsigned short* __restrict__ P) {
  int gid = blockIdx.x * blockDim.x + threadIdx.x;
  if (gid >= N1G + N2G + N3G) return;
  unsigned short v[8];
  unsigned short* dst;
  if (gid < N1G) {
    int lane = gid & 63, t = (gid >> 6) & 15, r = gid >> 10;
    int qq = lane >> 4, mm = lane & 15;
    #pragma unroll
    for (int j = 0; j < 8; ++j) {
      int k = 8*qq + j;
      v[j] = (k < 22) ? f2bf(W1[(r*22 + k)*256 + 16*t + mm]) : (unsigned short)0;
    }
    dst = P + (size_t)gid * 8;
  } else if (gid < N1G + N2G) {
    int g = gid - N1G;
    int lane = g & 63, c = (g >> 6) & 7, t = (g >> 9) & 15, r = g >> 13;
    int qq = lane >> 4, mm = lane & 15;
    #pragma unroll
    for (int j = 0; j < 8; ++j) {
      int k = 32*c + 8*qq + j;
      v[j] = f2bf(W2[((size_t)r*256 + k)*256 + 16*t + mm]);
    }
    dst = P + (size_t)(N1G + g) * 8;
  } else {
    int g = gid - N1G - N2G;
    int lane = g & 63, c = (g >> 6) & 7, r = g >> 9;
    int qq = lane >> 4, mm = lane & 15;
    #pragma unroll
    for (int j = 0; j < 8; ++j) {
      int k = 32*c + 8*qq + j;
      v[j] = f2bf(W3[(r*256 + k)*16 + mm]);
    }
    dst = P + (size_t)(N1G + N2G + g) * 8;
  }
  ushort4v lo = { v[0],v[1],v[2],v[3] }, hi = { v[4],v[5],v[6],v[7] };
  *(ushort4v*)dst = lo;
  *(ushort4v*)(dst + 4) = hi;
}

// ---------------------------------------------------------------------------
#define SX 40    // xhi/xlo row stride (ushorts): 20 words, bank-friendly, 16B-mult
#define SH 264   // h row stride: 132 words
#define SM 66    // msg row stride: 33 words (breaks the all-rows-same-bank 32)

__global__ __launch_bounds__(256, 4) void md5_main(
    const float* __restrict__ msg,   // (16384,64)
    const float* __restrict__ st0,   // (16384,16)
    const float* __restrict__ b1,    // (64,256)
    const float* __restrict__ b2,    // (64,256)
    const float* __restrict__ b3,    // (64,16)
    const unsigned short* __restrict__ P,
    float* __restrict__ out)         // (16384,16)
{
  __shared__ unsigned short xhi[16][SX], xlo[16][SX];
  __shared__ unsigned short hA[16][SH], hB[16][SH];
  __shared__ unsigned short msgb[16][SM], msgl[16][SM];

  const int tid  = threadIdx.x;
  const int wv   = tid >> 6;
  const int lane = tid & 63;
  const int q    = lane >> 4;
  const int ln   = lane & 15;
  const int row0 = blockIdx.x * 16;

  const unsigned short* P1 = P;
  const unsigned short* P2 = P + (size_t)N1G * 8;
  const unsigned short* P3 = P + (size_t)(N1G + N2G) * 8;

  // zero x buffers (pad features 22..31 must be 0 forever)
  for (int i = tid; i < 16*SX; i += 256) { (&xhi[0][0])[i] = 0; (&xlo[0][0])[i] = 0; }
  // msg preload (16 rows x 64), hi/lo split
  {
    int idx = tid * 4, rr = idx >> 6, cc = idx & 63;
    floatx4 v = *(const floatx4*)(msg + (size_t)(row0 + rr)*64 + cc);
    #pragma unroll
    for (int j = 0; j < 4; ++j) {
      unsigned short h = f2bf(v[j]);
      msgb[rr][cc + j] = h;
      msgl[rr][cc + j] = f2bf(v[j] - bf2f(h));
    }
  }
  __syncthreads();
  if (wv == 0) {
    floatx4 v = *(const floatx4*)(st0 + (size_t)(row0 + ln)*16 + 4*q);
    #pragma unroll
    for (int e = 0; e < 4; ++e) {
      unsigned short h = f2bf(v[e]);
      xhi[ln][4*q + e] = h;
      xlo[ln][4*q + e] = f2bf(v[e] - bf2f(h));
    }
  } else if (wv == 1 && lane < 16) {
    int n = lane, s = c_sched[0];
    float i1 = c_shift[0] / 25.0f;
    unsigned short i1h = f2bf(i1), i1l = f2bf(i1 - bf2f(i1h));
    #pragma unroll
    for (int j = 0; j < 4; ++j) { xhi[n][16+j] = msgb[n][4*s+j]; xlo[n][16+j] = msgl[n][4*s+j]; }
    xhi[n][20] = 0;   xlo[n][20] = 0;     // round 0: i/64 = 0
    xhi[n][21] = i1h; xlo[n][21] = i1l;
  }

  #pragma unroll 1
  for (int r = 0; r < 64; ++r) {
    __syncthreads();                       // (A) x ready, hA free

    // -------- Layer 1: x(22,hi/lo) @ W1 -> h1 (bf16) --------
    bf16x8 bxh = *(const bf16x8*)&xhi[ln][8*q];
    bf16x8 bxl = *(const bf16x8*)&xlo[ln][8*q];
    const unsigned short* p1 = P1 + ((size_t)(r*16 + 4*wv)*64 + lane)*8;
    #pragma unroll
    for (int tt = 0; tt < 4; ++tt) {
      bf16x8 a = *(const bf16x8*)(p1 + (size_t)tt*512);
      floatx4 acc = {0,0,0,0};
      acc = mfma16(a, bxl, acc);
      acc = mfma16(a, bxh, acc);
      int f0 = (4*wv + tt)*16 + 4*q;
      floatx4 bb = *(const floatx4*)(b1 + r*256 + f0);
      ushort4v h4;
      #pragma unroll
      for (int e = 0; e < 4; ++e) h4[e] = f2bf(gelu_f(acc[e] + bb[e]));
      *(ushort4v*)&hA[ln][f0] = h4;
    }
    __syncthreads();                       // (B) h1 ready, hB free

    // -------- Layer 2: h1 @ W2 -> h2 (bf16) --------
    bf16x8 Bf[8];
    #pragma unroll
    for (int c = 0; c < 8; ++c) Bf[c] = *(const bf16x8*)&hA[ln][32*c + 8*q];
    const unsigned short* p2 = P2 + ((size_t)((r*16 + 4*wv)*8)*64 + lane)*8;
    #pragma unroll
    for (int tt = 0; tt < 4; ++tt) {
      floatx4 acc = {0,0,0,0};
      #pragma unroll
      for (int c = 0; c < 8; ++c) {
        bf16x8 a = *(const bf16x8*)(p2 + (size_t)(tt*8 + c)*512);
        acc = mfma16(a, Bf[c], acc);
      }
      int f0 = (4*wv + tt)*16 + 4*q;
      floatx4 bb = *(const floatx4*)(b2 + r*256 + f0);
      ushort4v h4;
      #pragma unroll
      for (int e = 0; e < 4; ++e) h4[e] = f2bf(gelu_f(acc[e] + bb[e]));
      *(ushort4v*)&hB[ln][f0] = h4;
    }

    // L3 A-fragment prefetch (wave0 only) BEFORE the barrier: hides VMEM latency
    bf16x8 a3[8];
    if (wv == 0) {
      const unsigned short* p3 = P3 + ((size_t)(r*8)*64 + lane)*8;
      #pragma unroll
      for (int c = 0; c < 8; ++c) a3[c] = *(const bf16x8*)(p3 + (size_t)c*512);
    }
    __syncthreads();                       // (C) h2 ready

    // -------- Layer 3: h2 @ W3 -> state(16), full-K by wave0 --------
    if (wv == 0) {
      floatx4 s = {0,0,0,0};
      #pragma unroll
      for (int c = 0; c < 8; ++c) {
        bf16x8 bh = *(const bf16x8*)&hB[ln][32*c + 8*q];
        s = mfma16(a3[c], bh, s);
      }
      s += *(const floatx4*)(b3 + r*16 + 4*q);
      if (r == 63) {
        *(floatx4*)(out + (size_t)(row0 + ln)*16 + 4*q) = s;
      } else {
        ushort4v h4, l4;
        #pragma unroll
        for (int e = 0; e < 4; ++e) {
          unsigned short h = f2bf(s[e]);
          h4[e] = h;
          l4[e] = f2bf(s[e] - bf2f(h));
        }
        *(ushort4v*)&xhi[ln][4*q] = h4;
        *(ushort4v*)&xlo[ln][4*q] = l4;
      }
    } else if (wv == 1 && lane < 16 && r < 63) {
      int n = lane, s = c_sched[r+1];
      float i0 = (float)(r+1) * 0.015625f;   // exact in bf16
      float i1 = c_shift[r+1] / 25.0f;
      unsigned short i1h = f2bf(i1), i1l = f2bf(i1 - bf2f(i1h));
      #pragma unroll
      for (int j = 0; j < 4; ++j) { xhi[n][16+j] = msgb[n][4*s+j]; xlo[n][16+j] = msgl[n][4*s+j]; }
      xhi[n][20] = f2bf(i0); xlo[n][20] = 0;
      xhi[n][21] = i1h;      xlo[n][21] = i1l;
    }
  }
}

// ---------------------------------------------------------------------------
extern "C" void kernel_launch(void* const* d_in, const int* in_sizes, int n_in,
                              void* d_out, int out_size, void* d_ws, size_t ws_size,
                              hipStream_t stream) {
  const float* msg = (const float*)d_in[0];
  const float* st0 = (const float*)d_in[1];
  const float* W1  = (const float*)d_in[2];
  const float* b1  = (const float*)d_in[3];
  const float* W2  = (const float*)d_in[4];
  const float* b2  = (const float*)d_in[5];
  const float* W3  = (const float*)d_in[6];
  const float* b3  = (const float*)d_in[7];
  float* out = (float*)d_out;
  (void)in_sizes; (void)n_in; (void)out_size; (void)ws_size;  // ws >= 9.96MB proven in R4

  unsigned short* P = (unsigned short*)d_ws;
  const int totalGroups = N1G + N2G + N3G;   // 622592
  pack_w<<<(totalGroups + 255) / 256, 256, 0, stream>>>(W1, W2, W3, P);
  md5_main<<<1024, 256, 0, stream>>>(msg, st0, b1, b2, b3, P, out);
}

// Round 7
// 575.913 us; speedup vs baseline: 7.9498x; 1.4156x over previous
//
#include <hip/hip_runtime.h>
#include <stdint.h>

// ---------------------------------------------------------------------------
// MD5Surrogate: 64-round scan of 3-layer MLP (22->256->256->16), B=16384.
// fp32 in/out. R7 = R6 with compile fix (split2 returns by value). 2 barriers
// per round: Layer 3 computed redundantly by ALL waves into per-wave private
// x-buffers (wave-local LDS round-trip replaces a block-wide barrier + serial
// wave0 section). State x kept as bf16 hi/lo split; h1/h2 bf16 (proven
// harmless). HW bf16 converts. Weights packed to MFMA A-frag order in d_ws.
// ---------------------------------------------------------------------------

using bf16x8   = __attribute__((ext_vector_type(8))) __bf16;
using floatx4  = __attribute__((ext_vector_type(4))) float;
using ushort4v = __attribute__((ext_vector_type(4))) unsigned short;

__constant__ int c_sched[64] = {
  0,1,2,3,4,5,6,7,8,9,10,11,12,13,14,15,
  1,6,11,0,5,10,15,4,9,14,3,8,13,2,7,12,
  5,8,11,14,1,4,7,10,13,0,3,6,9,12,15,2,
  0,7,14,5,12,3,10,1,8,15,6,13,4,11,2,9
};
__constant__ float c_shift[64] = {
  7,12,17,22,7,12,17,22,7,12,17,22,7,12,17,22,
  5,9,14,20,5,9,14,20,5,9,14,20,5,9,14,20,
  4,11,16,23,4,11,16,23,4,11,16,23,4,11,16,23,
  6,10,15,21,6,10,15,21,6,10,15,21,6,10,15,21
};

__device__ __forceinline__ unsigned short bfbits(__bf16 b) {
  union { __bf16 b; unsigned short u; } v; v.b = b; return v.u;
}
// exact gelu: 0.5*x*(1+erf(x/sqrt(2))), erf via Abramowitz-Stegun 7.1.26
__device__ __forceinline__ float gelu_f(float x) {
  float ax = fabsf(x) * 0.7071067811865476f;
  float t  = __builtin_amdgcn_rcpf(1.0f + 0.3275911f * ax);
  float poly = t*(0.254829592f + t*(-0.284496736f + t*(1.421413741f +
               t*(-1.453152027f + t*1.061405429f))));
  float e  = __expf(-ax*ax);
  float er = 1.0f - poly*e;
  er = copysignf(er, x);
  return 0.5f * x * (1.0f + er);
}
__device__ __forceinline__ floatx4 mfma16(bf16x8 a, bf16x8 b, floatx4 c) {
  return __builtin_amdgcn_mfma_f32_16x16x32_bf16(a, b, c, 0, 0, 0);
}
// split f into bf16 hi + bf16 lo (HW converts), return by value
struct BfPair { unsigned short h, l; };
__device__ __forceinline__ BfPair split2(float s) {
  __bf16 hb = (__bf16)s;
  __bf16 lb = (__bf16)(s - (float)hb);
  BfPair p; p.h = bfbits(hb); p.l = bfbits(lb); return p;
}

// ---------------------------------------------------------------------------
// Packed-weight layout: fragment = 64 lanes x 8 bf16. A[m][k]: m=lane&15,
// k=8*(lane>>4)+j.  P1 (r*16+t): W1[r][k][16t+m] (k>=22 -> 0)
//                   P2 ((r*16+t)*8+c): W2[r][32c+k'][16t+m]
//                   P3 (r*8+c): W3[r][32c+k'][m]
// ---------------------------------------------------------------------------
#define N1G (64*16*64)
#define N2G (64*16*8*64)
#define N3G (64*8*64)

__global__ void pack_w(const float* __restrict__ W1,
                       const float* __restrict__ W2,
                       const float* __restrict__ W3,
                       unsigned short* __restrict__ P) {
  int gid = blockIdx.x * blockDim.x + threadIdx.x;
  if (gid >= N1G + N2G + N3G) return;
  unsigned short v[8];
  unsigned short* dst;
  if (gid < N1G) {
    int lane = gid & 63, t = (gid >> 6) & 15, r = gid >> 10;
    int qq = lane >> 4, mm = lane & 15;
    #pragma unroll
    for (int j = 0; j < 8; ++j) {
      int k = 8*qq + j;
      v[j] = (k < 22) ? bfbits((__bf16)W1[(r*22 + k)*256 + 16*t + mm]) : (unsigned short)0;
    }
    dst = P + (size_t)gid * 8;
  } else if (gid < N1G + N2G) {
    int g = gid - N1G;
    int lane = g & 63, c = (g >> 6) & 7, t = (g >> 9) & 15, r = g >> 13;
    int qq = lane >> 4, mm = lane & 15;
    #pragma unroll
    for (int j = 0; j < 8; ++j) {
      int k = 32*c + 8*qq + j;
      v[j] = bfbits((__bf16)W2[((size_t)r*256 + k)*256 + 16*t + mm]);
    }
    dst = P + (size_t)(N1G + g) * 8;
  } else {
    int g = gid - N1G - N2G;
    int lane = g & 63, c = (g >> 6) & 7, r = g >> 9;
    int qq = lane >> 4, mm = lane & 15;
    #pragma unroll
    for (int j = 0; j < 8; ++j) {
      int k = 32*c + 8*qq + j;
      v[j] = bfbits((__bf16)W3[(r*256 + k)*16 + mm]);
    }
    dst = P + (size_t)(N1G + N2G + g) * 8;
  }
  ushort4v lo = { v[0],v[1],v[2],v[3] }, hi = { v[4],v[5],v[6],v[7] };
  *(ushort4v*)dst = lo;
  *(ushort4v*)(dst + 4) = hi;
}

// ---------------------------------------------------------------------------
#define SXW 36   // per-wave x row stride (ushorts)
#define SH 264   // h row stride
#define SM 66    // msg row stride

__global__ __launch_bounds__(256, 4) void md5_main(
    const float* __restrict__ msg,   // (16384,64)
    const float* __restrict__ st0,   // (16384,16)
    const float* __restrict__ b1,    // (64,256)
    const float* __restrict__ b2,    // (64,256)
    const float* __restrict__ b3,    // (64,16)
    const unsigned short* __restrict__ P,
    float* __restrict__ out)         // (16384,16)
{
  __shared__ unsigned short xh[4][16][SXW], xl[4][16][SXW];   // per-wave
  __shared__ unsigned short hA[16][SH], hB[16][SH];
  __shared__ unsigned short msgb[16][SM], msgl[16][SM];

  const int tid  = threadIdx.x;
  const int wv   = tid >> 6;
  const int lane = tid & 63;
  const int q    = lane >> 4;
  const int ln   = lane & 15;
  const int row0 = blockIdx.x * 16;

  const unsigned short* P1 = P;
  const unsigned short* P2 = P + (size_t)N1G * 8;
  const unsigned short* P3 = P + (size_t)(N1G + N2G) * 8;

  // zero own x buffers (pad cols must stay 0)
  for (int i = lane; i < 16*SXW; i += 64) {
    (&xh[wv][0][0])[i] = 0; (&xl[wv][0][0])[i] = 0;
  }
  // msg preload (shared, hi/lo)
  {
    int idx = tid * 4, rr = idx >> 6, cc = idx & 63;
    floatx4 v = *(const floatx4*)(msg + (size_t)(row0 + rr)*64 + cc);
    #pragma unroll
    for (int j = 0; j < 4; ++j) {
      BfPair p = split2(v[j]);
      msgb[rr][cc + j] = p.h;
      msgl[rr][cc + j] = p.l;
    }
  }
  // init own x: state, C-layout store shape
  {
    floatx4 v = *(const floatx4*)(st0 + (size_t)(row0 + ln)*16 + 4*q);
    ushort4v h4, l4;
    #pragma unroll
    for (int e = 0; e < 4; ++e) { BfPair p = split2(v[e]); h4[e] = p.h; l4[e] = p.l; }
    *(ushort4v*)&xh[wv][ln][4*q] = h4;
    *(ushort4v*)&xl[wv][ln][4*q] = l4;
  }
  __syncthreads();   // msgb/msgl ready (and all x-zeroing done)
  if (lane < 16) {
    int n = lane, s = c_sched[0];
    BfPair i1p = split2(c_shift[0] / 25.0f);
    #pragma unroll
    for (int j = 0; j < 4; ++j) { xh[wv][n][16+j] = msgb[n][4*s+j]; xl[wv][n][16+j] = msgl[n][4*s+j]; }
    xh[wv][n][20] = 0;     xl[wv][n][20] = 0;     // round 0: i/64 = 0
    xh[wv][n][21] = i1p.h; xl[wv][n][21] = i1p.l;
  }

  #pragma unroll 1
  for (int r = 0; r < 64; ++r) {
    // -------- Layer 1: own x (hi/lo) @ W1 -> h1 (bf16, shared) --------
    bf16x8 bxh = *(const bf16x8*)&xh[wv][ln][8*q];
    bf16x8 bxl = *(const bf16x8*)&xl[wv][ln][8*q];
    const unsigned short* p1 = P1 + ((size_t)(r*16 + 4*wv)*64 + lane)*8;
    #pragma unroll
    for (int tt = 0; tt < 4; ++tt) {
      bf16x8 a = *(const bf16x8*)(p1 + (size_t)tt*512);
      floatx4 acc = {0,0,0,0};
      acc = mfma16(a, bxl, acc);
      acc = mfma16(a, bxh, acc);
      int f0 = (4*wv + tt)*16 + 4*q;
      floatx4 bb = *(const floatx4*)(b1 + r*256 + f0);
      ushort4v h4;
      #pragma unroll
      for (int e = 0; e < 4; ++e) h4[e] = bfbits((__bf16)gelu_f(acc[e] + bb[e]));
      *(ushort4v*)&hA[ln][f0] = h4;
    }
    __syncthreads();                       // (B) h1 ready; hB free

    // -------- Layer 2: h1 @ W2 -> h2 (bf16, shared) --------
    bf16x8 Bf[8];
    #pragma unroll
    for (int c = 0; c < 8; ++c) Bf[c] = *(const bf16x8*)&hA[ln][32*c + 8*q];
    const unsigned short* p2 = P2 + ((size_t)((r*16 + 4*wv)*8)*64 + lane)*8;
    #pragma unroll
    for (int tt = 0; tt < 4; ++tt) {
      floatx4 acc = {0,0,0,0};
      #pragma unroll
      for (int c = 0; c < 8; ++c) {
        bf16x8 a = *(const bf16x8*)(p2 + (size_t)(tt*8 + c)*512);
        acc = mfma16(a, Bf[c], acc);
      }
      int f0 = (4*wv + tt)*16 + 4*q;
      floatx4 bb = *(const floatx4*)(b2 + r*256 + f0);
      ushort4v h4;
      #pragma unroll
      for (int e = 0; e < 4; ++e) h4[e] = bfbits((__bf16)gelu_f(acc[e] + bb[e]));
      *(ushort4v*)&hB[ln][f0] = h4;
    }
    // prefetch L3 A-frags (all waves) before the barrier
    bf16x8 a3[8];
    {
      const unsigned short* p3 = P3 + ((size_t)(r*8)*64 + lane)*8;
      #pragma unroll
      for (int c = 0; c < 8; ++c) a3[c] = *(const bf16x8*)(p3 + (size_t)c*512);
    }
    __syncthreads();                       // (C) h2 ready

    // -------- Layer 3 (redundant on every wave): h2 @ W3 -> new state ------
    {
      floatx4 s = {0,0,0,0};
      #pragma unroll
      for (int c = 0; c < 8; ++c) {
        bf16x8 bh = *(const bf16x8*)&hB[ln][32*c + 8*q];
        s = mfma16(a3[c], bh, s);
      }
      s += *(const floatx4*)(b3 + r*16 + 4*q);
      if (r == 63) {
        if (wv == 0)
          *(floatx4*)(out + (size_t)(row0 + ln)*16 + 4*q) = s;
      } else {
        ushort4v h4, l4;
        #pragma unroll
        for (int e = 0; e < 4; ++e) { BfPair p = split2(s[e]); h4[e] = p.h; l4[e] = p.l; }
        *(ushort4v*)&xh[wv][ln][4*q] = h4;
        *(ushort4v*)&xl[wv][ln][4*q] = l4;
        // word + rinfo for next round (own copy, wave-local)
        if (lane < 16) {
          int n = lane, sc = c_sched[r+1];
          float i0 = (float)(r+1) * 0.015625f;   // exact in bf16
          BfPair i1p = split2(c_shift[r+1] / 25.0f);
          #pragma unroll
          for (int j = 0; j < 4; ++j) { xh[wv][n][16+j] = msgb[n][4*sc+j]; xl[wv][n][16+j] = msgl[n][4*sc+j]; }
          xh[wv][n][20] = bfbits((__bf16)i0); xl[wv][n][20] = 0;
          xh[wv][n][21] = i1p.h;              xl[wv][n][21] = i1p.l;
        }
      }
    }
    // no barrier here: next L1 reads only this wave's own x buffers
  }
}

// ---------------------------------------------------------------------------
extern "C" void kernel_launch(void* const* d_in, const int* in_sizes, int n_in,
                              void* d_out, int out_size, void* d_ws, size_t ws_size,
                              hipStream_t stream) {
  const float* msg = (const float*)d_in[0];
  const float* st0 = (const float*)d_in[1];
  const float* W1  = (const float*)d_in[2];
  const float* b1  = (const float*)d_in[3];
  const float* W2  = (const float*)d_in[4];
  const float* b2  = (const float*)d_in[5];
  const float* W3  = (const float*)d_in[6];
  const float* b3  = (const float*)d_in[7];
  float* out = (float*)d_out;
  (void)in_sizes; (void)n_in; (void)out_size; (void)ws_size;

  unsigned short* P = (unsigned short*)d_ws;
  const int totalGroups = N1G + N2G + N3G;   // 622592
  pack_w<<<(totalGroups + 255) / 256, 256, 0, stream>>>(W1, W2, W3, P);
  md5_main<<<1024, 256, 0, stream>>>(msg, st0, b1, b2, b3, P, out);
}

// Round 9
// 563.323 us; speedup vs baseline: 8.1274x; 1.0224x over previous
//
#include <hip/hip_runtime.h>
#include <stdint.h>

// ---------------------------------------------------------------------------
// MD5Surrogate: 64-round scan of 3-layer MLP (22->256->256->16), B=16384.
// fp32 in/out. R9 = R8 with exp2 intrinsic name fixed. (a) A&S 7.1.25 gelu
// (3-term, |eps|<=2.5e-5, folded constants, exp2-scaled), (b) bias preloaded
// into MFMA accumulators, (c) L3 A-frag + b3 loads hoisted to start of L2.
// Structure: 2 barriers/round, per-wave private x buffers, redundant L3.
// ---------------------------------------------------------------------------

using bf16x8   = __attribute__((ext_vector_type(8))) __bf16;
using floatx4  = __attribute__((ext_vector_type(4))) float;
using ushort4v = __attribute__((ext_vector_type(4))) unsigned short;

__constant__ int c_sched[64] = {
  0,1,2,3,4,5,6,7,8,9,10,11,12,13,14,15,
  1,6,11,0,5,10,15,4,9,14,3,8,13,2,7,12,
  5,8,11,14,1,4,7,10,13,0,3,6,9,12,15,2,
  0,7,14,5,12,3,10,1,8,15,6,13,4,11,2,9
};
__constant__ float c_shift[64] = {
  7,12,17,22,7,12,17,22,7,12,17,22,7,12,17,22,
  5,9,14,20,5,9,14,20,5,9,14,20,5,9,14,20,
  4,11,16,23,4,11,16,23,4,11,16,23,4,11,16,23,
  6,10,15,21,6,10,15,21,6,10,15,21,6,10,15,21
};

__device__ __forceinline__ unsigned short bfbits(__bf16 b) {
  union { __bf16 b; unsigned short u; } v; v.b = b; return v.u;
}
// gelu via A&S 7.1.25: erf(z)=1-(a1 t+a2 t^2+a3 t^3)e^{-z^2}, t=1/(1+pz),
// |eps|<=2.5e-5. z=|x|/sqrt2 folded: denom=1+0.332702*|x|;
// e^{-x^2/2} = exp2(-x^2 * log2(e)/2) = exp2(-x^2*0.72134752)
__device__ __forceinline__ float gelu_f(float x) {
  float ax = fabsf(x);
  float t  = __builtin_amdgcn_rcpf(__builtin_fmaf(0.33270222f, ax, 1.0f));
  float e  = __builtin_amdgcn_exp2f(x * x * -0.72134752f);
  float poly = t * __builtin_fmaf(t, __builtin_fmaf(t, 0.7478556f, -0.0958798f),
                                  0.3480242f);
  float er = __builtin_fmaf(-poly, e, 1.0f);     // erf(|x|/sqrt2)
  er = copysignf(er, x);
  float hx = 0.5f * x;
  return __builtin_fmaf(hx, er, hx);             // 0.5x(1+erf)
}
__device__ __forceinline__ floatx4 mfma16(bf16x8 a, bf16x8 b, floatx4 c) {
  return __builtin_amdgcn_mfma_f32_16x16x32_bf16(a, b, c, 0, 0, 0);
}
struct BfPair { unsigned short h, l; };
__device__ __forceinline__ BfPair split2(float s) {
  __bf16 hb = (__bf16)s;
  __bf16 lb = (__bf16)(s - (float)hb);
  BfPair p; p.h = bfbits(hb); p.l = bfbits(lb); return p;
}

// ---------------------------------------------------------------------------
// Packed-weight layout: fragment = 64 lanes x 8 bf16. A[m][k]: m=lane&15,
// k=8*(lane>>4)+j.  P1 (r*16+t): W1[r][k][16t+m] (k>=22 -> 0)
//                   P2 ((r*16+t)*8+c): W2[r][32c+k'][16t+m]
//                   P3 (r*8+c): W3[r][32c+k'][m]
// ---------------------------------------------------------------------------
#define N1G (64*16*64)
#define N2G (64*16*8*64)
#define N3G (64*8*64)

__global__ void pack_w(const float* __restrict__ W1,
                       const float* __restrict__ W2,
                       const float* __restrict__ W3,
                       unsigned short* __restrict__ P) {
  int gid = blockIdx.x * blockDim.x + threadIdx.x;
  if (gid >= N1G + N2G + N3G) return;
  unsigned short v[8];
  unsigned short* dst;
  if (gid < N1G) {
    int lane = gid & 63, t = (gid >> 6) & 15, r = gid >> 10;
    int qq = lane >> 4, mm = lane & 15;
    #pragma unroll
    for (int j = 0; j < 8; ++j) {
      int k = 8*qq + j;
      v[j] = (k < 22) ? bfbits((__bf16)W1[(r*22 + k)*256 + 16*t + mm]) : (unsigned short)0;
    }
    dst = P + (size_t)gid * 8;
  } else if (gid < N1G + N2G) {
    int g = gid - N1G;
    int lane = g & 63, c = (g >> 6) & 7, t = (g >> 9) & 15, r = g >> 13;
    int qq = lane >> 4, mm = lane & 15;
    #pragma unroll
    for (int j = 0; j < 8; ++j) {
      int k = 32*c + 8*qq + j;
      v[j] = bfbits((__bf16)W2[((size_t)r*256 + k)*256 + 16*t + mm]);
    }
    dst = P + (size_t)(N1G + g) * 8;
  } else {
    int g = gid - N1G - N2G;
    int lane = g & 63, c = (g >> 6) & 7, r = g >> 9;
    int qq = lane >> 4, mm = lane & 15;
    #pragma unroll
    for (int j = 0; j < 8; ++j) {
      int k = 32*c + 8*qq + j;
      v[j] = bfbits((__bf16)W3[(r*256 + k)*16 + mm]);
    }
    dst = P + (size_t)(N1G + N2G + g) * 8;
  }
  ushort4v lo = { v[0],v[1],v[2],v[3] }, hi = { v[4],v[5],v[6],v[7] };
  *(ushort4v*)dst = lo;
  *(ushort4v*)(dst + 4) = hi;
}

// ---------------------------------------------------------------------------
#define SXW 36   // per-wave x row stride (ushorts)
#define SH 264   // h row stride
#define SM 66    // msg row stride

__global__ __launch_bounds__(256, 4) void md5_main(
    const float* __restrict__ msg,   // (16384,64)
    const float* __restrict__ st0,   // (16384,16)
    const float* __restrict__ b1,    // (64,256)
    const float* __restrict__ b2,    // (64,256)
    const float* __restrict__ b3,    // (64,16)
    const unsigned short* __restrict__ P,
    float* __restrict__ out)         // (16384,16)
{
  __shared__ unsigned short xh[4][16][SXW], xl[4][16][SXW];   // per-wave
  __shared__ unsigned short hA[16][SH], hB[16][SH];
  __shared__ unsigned short msgb[16][SM], msgl[16][SM];

  const int tid  = threadIdx.x;
  const int wv   = tid >> 6;
  const int lane = tid & 63;
  const int q    = lane >> 4;
  const int ln   = lane & 15;
  const int row0 = blockIdx.x * 16;

  const unsigned short* P1 = P;
  const unsigned short* P2 = P + (size_t)N1G * 8;
  const unsigned short* P3 = P + (size_t)(N1G + N2G) * 8;

  // zero own x buffers (pad cols must stay 0)
  for (int i = lane; i < 16*SXW; i += 64) {
    (&xh[wv][0][0])[i] = 0; (&xl[wv][0][0])[i] = 0;
  }
  // msg preload (shared, hi/lo)
  {
    int idx = tid * 4, rr = idx >> 6, cc = idx & 63;
    floatx4 v = *(const floatx4*)(msg + (size_t)(row0 + rr)*64 + cc);
    #pragma unroll
    for (int j = 0; j < 4; ++j) {
      BfPair p = split2(v[j]);
      msgb[rr][cc + j] = p.h;
      msgl[rr][cc + j] = p.l;
    }
  }
  // init own x: state, C-layout store shape
  {
    floatx4 v = *(const floatx4*)(st0 + (size_t)(row0 + ln)*16 + 4*q);
    ushort4v h4, l4;
    #pragma unroll
    for (int e = 0; e < 4; ++e) { BfPair p = split2(v[e]); h4[e] = p.h; l4[e] = p.l; }
    *(ushort4v*)&xh[wv][ln][4*q] = h4;
    *(ushort4v*)&xl[wv][ln][4*q] = l4;
  }
  __syncthreads();   // msgb/msgl ready (and all x-zeroing done)
  if (lane < 16) {
    int n = lane, s = c_sched[0];
    BfPair i1p = split2(c_shift[0] / 25.0f);
    #pragma unroll
    for (int j = 0; j < 4; ++j) { xh[wv][n][16+j] = msgb[n][4*s+j]; xl[wv][n][16+j] = msgl[n][4*s+j]; }
    xh[wv][n][20] = 0;     xl[wv][n][20] = 0;     // round 0: i/64 = 0
    xh[wv][n][21] = i1p.h; xl[wv][n][21] = i1p.l;
  }

  #pragma unroll 1
  for (int r = 0; r < 64; ++r) {
    // -------- Layer 1: own x (hi/lo) @ W1 -> h1 (bf16, shared) --------
    // bias preloaded into accumulators; A-frags loaded up-front
    floatx4 bb1[4];
    bf16x8  a1[4];
    const unsigned short* p1 = P1 + ((size_t)(r*16 + 4*wv)*64 + lane)*8;
    #pragma unroll
    for (int tt = 0; tt < 4; ++tt) {
      a1[tt]  = *(const bf16x8*)(p1 + (size_t)tt*512);
      bb1[tt] = *(const floatx4*)(b1 + r*256 + (4*wv + tt)*16 + 4*q);
    }
    bf16x8 bxh = *(const bf16x8*)&xh[wv][ln][8*q];
    bf16x8 bxl = *(const bf16x8*)&xl[wv][ln][8*q];
    #pragma unroll
    for (int tt = 0; tt < 4; ++tt) {
      floatx4 acc = bb1[tt];
      acc = mfma16(a1[tt], bxl, acc);
      acc = mfma16(a1[tt], bxh, acc);
      int f0 = (4*wv + tt)*16 + 4*q;
      ushort4v h4;
      #pragma unroll
      for (int e = 0; e < 4; ++e) h4[e] = bfbits((__bf16)gelu_f(acc[e]));
      *(ushort4v*)&hA[ln][f0] = h4;
    }
    __syncthreads();                       // (B) h1 ready; hB free

    // -------- Layer 2: h1 @ W2 -> h2 (bf16, shared) --------
    // hoist L3 A-frags + b3 + b2 biases first: latency hides under L2 compute
    bf16x8 a3[8];
    {
      const unsigned short* p3 = P3 + ((size_t)(r*8)*64 + lane)*8;
      #pragma unroll
      for (int c = 0; c < 8; ++c) a3[c] = *(const bf16x8*)(p3 + (size_t)c*512);
    }
    floatx4 bb3 = *(const floatx4*)(b3 + r*16 + 4*q);
    floatx4 bb2[4];
    #pragma unroll
    for (int tt = 0; tt < 4; ++tt)
      bb2[tt] = *(const floatx4*)(b2 + r*256 + (4*wv + tt)*16 + 4*q);

    bf16x8 Bf[8];
    #pragma unroll
    for (int c = 0; c < 8; ++c) Bf[c] = *(const bf16x8*)&hA[ln][32*c + 8*q];
    const unsigned short* p2 = P2 + ((size_t)((r*16 + 4*wv)*8)*64 + lane)*8;
    #pragma unroll
    for (int tt = 0; tt < 4; ++tt) {
      floatx4 acc = bb2[tt];
      #pragma unroll
      for (int c = 0; c < 8; ++c) {
        bf16x8 a = *(const bf16x8*)(p2 + (size_t)(tt*8 + c)*512);
        acc = mfma16(a, Bf[c], acc);
      }
      int f0 = (4*wv + tt)*16 + 4*q;
      ushort4v h4;
      #pragma unroll
      for (int e = 0; e < 4; ++e) h4[e] = bfbits((__bf16)gelu_f(acc[e]));
      *(ushort4v*)&hB[ln][f0] = h4;
    }
    __syncthreads();                       // (C) h2 ready

    // -------- Layer 3 (redundant on every wave): h2 @ W3 -> new state ------
    {
      floatx4 s = bb3;
      #pragma unroll
      for (int c = 0; c < 8; ++c) {
        bf16x8 bh = *(const bf16x8*)&hB[ln][32*c + 8*q];
        s = mfma16(a3[c], bh, s);
      }
      if (r == 63) {
        if (wv == 0)
          *(floatx4*)(out + (size_t)(row0 + ln)*16 + 4*q) = s;
      } else {
        ushort4v h4, l4;
        #pragma unroll
        for (int e = 0; e < 4; ++e) { BfPair p = split2(s[e]); h4[e] = p.h; l4[e] = p.l; }
        *(ushort4v*)&xh[wv][ln][4*q] = h4;
        *(ushort4v*)&xl[wv][ln][4*q] = l4;
        // word + rinfo for next round (own copy, wave-local)
        if (lane < 16) {
          int n = lane, sc = c_sched[r+1];
          float i0 = (float)(r+1) * 0.015625f;   // exact in bf16
          BfPair i1p = split2(c_shift[r+1] / 25.0f);
          #pragma unroll
          for (int j = 0; j < 4; ++j) { xh[wv][n][16+j] = msgb[n][4*sc+j]; xl[wv][n][16+j] = msgl[n][4*sc+j]; }
          xh[wv][n][20] = bfbits((__bf16)i0); xl[wv][n][20] = 0;
          xh[wv][n][21] = i1p.h;              xl[wv][n][21] = i1p.l;
        }
      }
    }
    // no barrier here: next L1 reads only this wave's own x buffers
  }
}

// ---------------------------------------------------------------------------
extern "C" void kernel_launch(void* const* d_in, const int* in_sizes, int n_in,
                              void* d_out, int out_size, void* d_ws, size_t ws_size,
                              hipStream_t stream) {
  const float* msg = (const float*)d_in[0];
  const float* st0 = (const float*)d_in[1];
  const float* W1  = (const float*)d_in[2];
  const float* b1  = (const float*)d_in[3];
  const float* W2  = (const float*)d_in[4];
  const float* b2  = (const float*)d_in[5];
  const float* W3  = (const float*)d_in[6];
  const float* b3  = (const float*)d_in[7];
  float* out = (float*)d_out;
  (void)in_sizes; (void)n_in; (void)out_size; (void)ws_size;

  unsigned short* P = (unsigned short*)d_ws;
  const int totalGroups = N1G + N2G + N3G;   // 622592
  pack_w<<<(totalGroups + 255) / 256, 256, 0, stream>>>(W1, W2, W3, P);
  md5_main<<<1024, 256, 0, stream>>>(msg, st0, b1, b2, b3, P, out);
}

// Round 10
// 466.398 us; speedup vs baseline: 9.8164x; 1.2078x over previous
//
#include <hip/hip_runtime.h>
#include <stdint.h>

// ---------------------------------------------------------------------------
// MD5Surrogate: 64-round scan of 3-layer MLP (22->256->256->16), B=16384.
// fp32 in/out. R10: TWO independent 16-row groups per block (32 rows, grid
// 512, 2 blocks/CU). Weight frags + biases loaded once per block serve both
// groups -> L2/L3 weight traffic halves (10.2GB -> 5.1GB/dispatch) and each
// wave has 2x independent work to hide L2 latency + barrier drains.
// Structure from R9: 2 barriers/round, per-wave private x (bf16 hi/lo),
// redundant L3 on all waves, A&S 7.1.25 gelu, bias-in-accumulator.
// ---------------------------------------------------------------------------

using bf16x8   = __attribute__((ext_vector_type(8))) __bf16;
using floatx4  = __attribute__((ext_vector_type(4))) float;
using ushort4v = __attribute__((ext_vector_type(4))) unsigned short;

__constant__ int c_sched[64] = {
  0,1,2,3,4,5,6,7,8,9,10,11,12,13,14,15,
  1,6,11,0,5,10,15,4,9,14,3,8,13,2,7,12,
  5,8,11,14,1,4,7,10,13,0,3,6,9,12,15,2,
  0,7,14,5,12,3,10,1,8,15,6,13,4,11,2,9
};
__constant__ float c_shift[64] = {
  7,12,17,22,7,12,17,22,7,12,17,22,7,12,17,22,
  5,9,14,20,5,9,14,20,5,9,14,20,5,9,14,20,
  4,11,16,23,4,11,16,23,4,11,16,23,4,11,16,23,
  6,10,15,21,6,10,15,21,6,10,15,21,6,10,15,21
};

__device__ __forceinline__ unsigned short bfbits(__bf16 b) {
  union { __bf16 b; unsigned short u; } v; v.b = b; return v.u;
}
// gelu via A&S 7.1.25 (|eps|<=2.5e-5), constants folded, exp2-scaled
__device__ __forceinline__ float gelu_f(float x) {
  float ax = fabsf(x);
  float t  = __builtin_amdgcn_rcpf(__builtin_fmaf(0.33270222f, ax, 1.0f));
  float e  = __builtin_amdgcn_exp2f(x * x * -0.72134752f);
  float poly = t * __builtin_fmaf(t, __builtin_fmaf(t, 0.7478556f, -0.0958798f),
                                  0.3480242f);
  float er = __builtin_fmaf(-poly, e, 1.0f);
  er = copysignf(er, x);
  float hx = 0.5f * x;
  return __builtin_fmaf(hx, er, hx);
}
__device__ __forceinline__ floatx4 mfma16(bf16x8 a, bf16x8 b, floatx4 c) {
  return __builtin_amdgcn_mfma_f32_16x16x32_bf16(a, b, c, 0, 0, 0);
}
struct BfPair { unsigned short h, l; };
__device__ __forceinline__ BfPair split2(float s) {
  __bf16 hb = (__bf16)s;
  __bf16 lb = (__bf16)(s - (float)hb);
  BfPair p; p.h = bfbits(hb); p.l = bfbits(lb); return p;
}

// ---------------------------------------------------------------------------
// Packed-weight layout: fragment = 64 lanes x 8 bf16. A[m][k]: m=lane&15,
// k=8*(lane>>4)+j.  P1 (r*16+t): W1[r][k][16t+m] (k>=22 -> 0)
//                   P2 ((r*16+t)*8+c): W2[r][32c+k'][16t+m]
//                   P3 (r*8+c): W3[r][32c+k'][m]
// ---------------------------------------------------------------------------
#define N1G (64*16*64)
#define N2G (64*16*8*64)
#define N3G (64*8*64)

__global__ void pack_w(const float* __restrict__ W1,
                       const float* __restrict__ W2,
                       const float* __restrict__ W3,
                       unsigned short* __restrict__ P) {
  int gid = blockIdx.x * blockDim.x + threadIdx.x;
  if (gid >= N1G + N2G + N3G) return;
  unsigned short v[8];
  unsigned short* dst;
  if (gid < N1G) {
    int lane = gid & 63, t = (gid >> 6) & 15, r = gid >> 10;
    int qq = lane >> 4, mm = lane & 15;
    #pragma unroll
    for (int j = 0; j < 8; ++j) {
      int k = 8*qq + j;
      v[j] = (k < 22) ? bfbits((__bf16)W1[(r*22 + k)*256 + 16*t + mm]) : (unsigned short)0;
    }
    dst = P + (size_t)gid * 8;
  } else if (gid < N1G + N2G) {
    int g = gid - N1G;
    int lane = g & 63, c = (g >> 6) & 7, t = (g >> 9) & 15, r = g >> 13;
    int qq = lane >> 4, mm = lane & 15;
    #pragma unroll
    for (int j = 0; j < 8; ++j) {
      int k = 32*c + 8*qq + j;
      v[j] = bfbits((__bf16)W2[((size_t)r*256 + k)*256 + 16*t + mm]);
    }
    dst = P + (size_t)(N1G + g) * 8;
  } else {
    int g = gid - N1G - N2G;
    int lane = g & 63, c = (g >> 6) & 7, r = g >> 9;
    int qq = lane >> 4, mm = lane & 15;
    #pragma unroll
    for (int j = 0; j < 8; ++j) {
      int k = 32*c + 8*qq + j;
      v[j] = bfbits((__bf16)W3[(r*256 + k)*16 + mm]);
    }
    dst = P + (size_t)(N1G + N2G + g) * 8;
  }
  ushort4v lo = { v[0],v[1],v[2],v[3] }, hi = { v[4],v[5],v[6],v[7] };
  *(ushort4v*)dst = lo;
  *(ushort4v*)(dst + 4) = hi;
}

// ---------------------------------------------------------------------------
#define NG  2    // row-groups per block
#define SXW 36   // per-wave x row stride (ushorts)
#define SH 264   // h row stride
#define SM 66    // msg row stride

__global__ __launch_bounds__(256, 2) void md5_main(
    const float* __restrict__ msg,   // (16384,64)
    const float* __restrict__ st0,   // (16384,16)
    const float* __restrict__ b1,    // (64,256)
    const float* __restrict__ b2,    // (64,256)
    const float* __restrict__ b3,    // (64,16)
    const unsigned short* __restrict__ P,
    float* __restrict__ out)         // (16384,16)
{
  __shared__ unsigned short xh[4][NG][16][SXW], xl[4][NG][16][SXW];
  __shared__ unsigned short hA[NG][16][SH], hB[NG][16][SH];
  __shared__ unsigned short msgb[NG*16][SM], msgl[NG*16][SM];

  const int tid  = threadIdx.x;
  const int wv   = tid >> 6;
  const int lane = tid & 63;
  const int q    = lane >> 4;
  const int ln   = lane & 15;
  const int row0 = blockIdx.x * (NG*16);

  const unsigned short* P1 = P;
  const unsigned short* P2 = P + (size_t)N1G * 8;
  const unsigned short* P3 = P + (size_t)(N1G + N2G) * 8;

  // zero own x buffers (pad cols must stay 0)
  for (int i = lane; i < NG*16*SXW; i += 64) {
    (&xh[wv][0][0][0])[i] = 0; (&xl[wv][0][0][0])[i] = 0;
  }
  // msg preload (shared, hi/lo): 32 rows x 64 = 2048 elems / 256 thr = 8 each
  {
    int idx = tid * 8, rr = idx >> 6, cc = idx & 63;
    floatx4 v0 = *(const floatx4*)(msg + (size_t)(row0 + rr)*64 + cc);
    floatx4 v1 = *(const floatx4*)(msg + (size_t)(row0 + rr)*64 + cc + 4);
    #pragma unroll
    for (int j = 0; j < 4; ++j) {
      BfPair p0 = split2(v0[j]);
      BfPair p1 = split2(v1[j]);
      msgb[rr][cc + j]     = p0.h;  msgl[rr][cc + j]     = p0.l;
      msgb[rr][cc + 4 + j] = p1.h;  msgl[rr][cc + 4 + j] = p1.l;
    }
  }
  // init own x: state for both groups (C-layout store shape)
  #pragma unroll
  for (int g = 0; g < NG; ++g) {
    floatx4 v = *(const floatx4*)(st0 + (size_t)(row0 + g*16 + ln)*16 + 4*q);
    ushort4v h4, l4;
    #pragma unroll
    for (int e = 0; e < 4; ++e) { BfPair p = split2(v[e]); h4[e] = p.h; l4[e] = p.l; }
    *(ushort4v*)&xh[wv][g][ln][4*q] = h4;
    *(ushort4v*)&xl[wv][g][ln][4*q] = l4;
  }
  __syncthreads();   // msgb/msgl ready (and all x-zeroing done)
  if (lane < NG*16) {
    int g = lane >> 4, n = lane & 15, rrow = lane;
    int s = c_sched[0];
    BfPair i1p = split2(c_shift[0] / 25.0f);
    #pragma unroll
    for (int j = 0; j < 4; ++j) {
      xh[wv][g][n][16+j] = msgb[rrow][4*s+j];
      xl[wv][g][n][16+j] = msgl[rrow][4*s+j];
    }
    xh[wv][g][n][20] = 0;     xl[wv][g][n][20] = 0;   // round 0: i/64 = 0
    xh[wv][g][n][21] = i1p.h; xl[wv][g][n][21] = i1p.l;
  }

  #pragma unroll 1
  for (int r = 0; r < 64; ++r) {
    // -------- Layer 1: x @ W1 -> h1 (both groups; frags/biases loaded once) --
    floatx4 bb1[4];
    bf16x8  a1[4];
    const unsigned short* p1 = P1 + ((size_t)(r*16 + 4*wv)*64 + lane)*8;
    #pragma unroll
    for (int tt = 0; tt < 4; ++tt) {
      a1[tt]  = *(const bf16x8*)(p1 + (size_t)tt*512);
      bb1[tt] = *(const floatx4*)(b1 + r*256 + (4*wv + tt)*16 + 4*q);
    }
    bf16x8 bxh[NG], bxl[NG];
    #pragma unroll
    for (int g = 0; g < NG; ++g) {
      bxh[g] = *(const bf16x8*)&xh[wv][g][ln][8*q];
      bxl[g] = *(const bf16x8*)&xl[wv][g][ln][8*q];
    }
    #pragma unroll
    for (int tt = 0; tt < 4; ++tt) {
      int f0 = (4*wv + tt)*16 + 4*q;
      #pragma unroll
      for (int g = 0; g < NG; ++g) {
        floatx4 acc = bb1[tt];
        acc = mfma16(a1[tt], bxl[g], acc);
        acc = mfma16(a1[tt], bxh[g], acc);
        ushort4v h4;
        #pragma unroll
        for (int e = 0; e < 4; ++e) h4[e] = bfbits((__bf16)gelu_f(acc[e]));
        *(ushort4v*)&hA[g][ln][f0] = h4;
      }
    }
    __syncthreads();                       // (B) h1 ready; hB free

    // -------- Layer 2: h1 @ W2 -> h2 (both groups) --------
    // hoist L3 A-frags + b3 + b2 biases: latency hides under L2 compute
    bf16x8 a3[8];
    {
      const unsigned short* p3 = P3 + ((size_t)(r*8)*64 + lane)*8;
      #pragma unroll
      for (int c = 0; c < 8; ++c) a3[c] = *(const bf16x8*)(p3 + (size_t)c*512);
    }
    floatx4 bb3 = *(const floatx4*)(b3 + r*16 + 4*q);
    floatx4 bb2[4];
    #pragma unroll
    for (int tt = 0; tt < 4; ++tt)
      bb2[tt] = *(const floatx4*)(b2 + r*256 + (4*wv + tt)*16 + 4*q);

    bf16x8 Bf[NG][8];
    #pragma unroll
    for (int g = 0; g < NG; ++g)
      #pragma unroll
      for (int c = 0; c < 8; ++c) Bf[g][c] = *(const bf16x8*)&hA[g][ln][32*c + 8*q];

    const unsigned short* p2 = P2 + ((size_t)((r*16 + 4*wv)*8)*64 + lane)*8;
    #pragma unroll
    for (int tt = 0; tt < 4; ++tt) {
      bf16x8 a2[8];
      #pragma unroll
      for (int c = 0; c < 8; ++c)
        a2[c] = *(const bf16x8*)(p2 + (size_t)(tt*8 + c)*512);
      int f0 = (4*wv + tt)*16 + 4*q;
      #pragma unroll
      for (int g = 0; g < NG; ++g) {
        floatx4 acc = bb2[tt];
        #pragma unroll
        for (int c = 0; c < 8; ++c) acc = mfma16(a2[c], Bf[g][c], acc);
        ushort4v h4;
        #pragma unroll
        for (int e = 0; e < 4; ++e) h4[e] = bfbits((__bf16)gelu_f(acc[e]));
        *(ushort4v*)&hB[g][ln][f0] = h4;
      }
    }
    __syncthreads();                       // (C) h2 ready

    // -------- Layer 3 (redundant on every wave, both groups) --------
    #pragma unroll
    for (int g = 0; g < NG; ++g) {
      floatx4 s = bb3;
      #pragma unroll
      for (int c = 0; c < 8; ++c) {
        bf16x8 bh = *(const bf16x8*)&hB[g][ln][32*c + 8*q];
        s = mfma16(a3[c], bh, s);
      }
      if (r == 63) {
        if (wv == 0)
          *(floatx4*)(out + (size_t)(row0 + g*16 + ln)*16 + 4*q) = s;
      } else {
        ushort4v h4, l4;
        #pragma unroll
        for (int e = 0; e < 4; ++e) { BfPair p = split2(s[e]); h4[e] = p.h; l4[e] = p.l; }
        *(ushort4v*)&xh[wv][g][ln][4*q] = h4;
        *(ushort4v*)&xl[wv][g][ln][4*q] = l4;
      }
    }
    // word + rinfo for next round (own copies, wave-local)
    if (lane < NG*16 && r < 63) {
      int g = lane >> 4, n = lane & 15, rrow = lane;
      int sc = c_sched[r+1];
      float i0 = (float)(r+1) * 0.015625f;   // exact in bf16
      BfPair i1p = split2(c_shift[r+1] / 25.0f);
      #pragma unroll
      for (int j = 0; j < 4; ++j) {
        xh[wv][g][n][16+j] = msgb[rrow][4*sc+j];
        xl[wv][g][n][16+j] = msgl[rrow][4*sc+j];
      }
      xh[wv][g][n][20] = bfbits((__bf16)i0); xl[wv][g][n][20] = 0;
      xh[wv][g][n][21] = i1p.h;              xl[wv][g][n][21] = i1p.l;
    }
    // no barrier here: next L1 reads only this wave's own x buffers
  }
}

// ---------------------------------------------------------------------------
extern "C" void kernel_launch(void* const* d_in, const int* in_sizes, int n_in,
                              void* d_out, int out_size, void* d_ws, size_t ws_size,
                              hipStream_t stream) {
  const float* msg = (const float*)d_in[0];
  const float* st0 = (const float*)d_in[1];
  const float* W1  = (const float*)d_in[2];
  const float* b1  = (const float*)d_in[3];
  const float* W2  = (const float*)d_in[4];
  const float* b2  = (const float*)d_in[5];
  const float* W3  = (const float*)d_in[6];
  const float* b3  = (const float*)d_in[7];
  float* out = (float*)d_out;
  (void)in_sizes; (void)n_in; (void)out_size; (void)ws_size;

  unsigned short* P = (unsigned short*)d_ws;
  const int totalGroups = N1G + N2G + N3G;   // 622592
  pack_w<<<(totalGroups + 255) / 256, 256, 0, stream>>>(W1, W2, W3, P);
  md5_main<<<512, 256, 0, stream>>>(msg, st0, b1, b2, b3, P, out);
}